// Round 8
// baseline (19227.040 us; speedup 1.0000x reference)
//
#include <hip/hip_runtime.h>
#include <hip/hip_bf16.h>

#define H      1000          // hidden dim
#define HP     1024          // padded hidden
#define TT     8192          // seq len
#define NC     68            // num chars
#define SL     64            // wave size
#define NWAVE  128           // 16 row slices x 8 col chunks
#define PRING  4             // packet ring slots
#define POLL_LIMIT 32768u    // sweeps before declaring the fast path dead
#define PF_LIMIT   8192u     // preflight-1 inv+load probe sweeps
#define PF2_LIMIT  1024u     // preflight-2 no-inv probe sweeps
#define BAR_LIMIT  16384u    // barrier spin limit (agent loads)
#define TM     16            // t-tile for output gemm
#define GRID_FAST 2048       // oversubscribed launch; cohort self-assembles on XCD 0
#define PF_MAGIC  0x1DEADBEEFull
#define PF2_MAGIC 0x2FEEDFACEull

typedef unsigned long long u64;
typedef long long ll;

// ---------------------------------------------------------------------------
// FAST PATH v8: r7-proven protocol + on-silicon test of "sc0 sc1 loads
// bypass L1", gating removal of the per-sweep buffer_inv.
//
// Evidence ledger:
//   r3/r7: plain coalesced 512B/wave stores + {buffer_inv sc0 +
//       global_load_dwordx2 sc0 sc1} polls => L2-resident (WRITE=32MB,
//       FETCH=6.6MB), completes, correct. r7 (batched poll, ONE waitcnt)
//       = 2.2us/step: batching 16 round trips -> 1 only bought 32->19ms,
//       so the dominant per-sweep cost is NOT load latency. Prime suspect:
//       buffer_inv (full L1 invalidate, ~1500cy, x4 waves/CU serializing).
//   r4/5/6 (WRITE=556MB): in-kernel MALL mode ran after the MODIFIED
//       preflight failed. r7's r3-exact preflight passes. Preflight-1 is
//       therefore frozen byte-for-byte.
//
// v8 preflight-2 (new, floor = r7): prime L1 with stale probe2 (plain
// load), barrier, rank0 plain-stores PF2_MAGIC, poll with EXACTLY the
// main-loop flavor {global_load_dwordx2 sc0 sc1, NO inv}, bounded. A wave
// that still reads stale flags ctrl[5]. Consensus:
//   ctrl[5]==0  => sc0 sc1 proven to ignore L1 content => main loop polls
//                  WITHOUT buffer_inv (drops the suspected ~1500cy/sweep).
//   else        => r7-proven inv poll (cost: r7 + ~0.1ms).
//
// Main loop (unchanged from r7 except the conditional inv):
//   publish: wave-contiguous 512B plain store of ((want<<32)|f32bits(a))
//   at pkt[slot][(b*8+cc)*64+rl] -> lands dirty in XCD-0 L2.
//   poll: [inv if needed] + 16x global_load_dwordx2 sc0 sc1 (2 bases,
//   imm offsets j*512B) + ONE s_waitcnt vmcnt(0); break when all 16 tags
//   (8 producers x 2 elements) == want.
//
// Correctness: tags absolute; payload rides in the same 8B word; fixed
// j-order sum + bases depending only on (cc,rl) => the 16 redundant
// finalizers compute bit-identical h. Self-zero of pkt_st kills cross-run
// stale tags. Ring safety (PRING=4): a producer storing @want+4 completed
// its poll @want+3, which transitively spans ALL 16 slices at @want+2 =>
// no poller of `want` sees a later generation.
//
// Liveness: all spins bounded; any overrun => wave returns; done stays < 8
// => proven fallback recomputes ALL of h_all. Preflight-2 failure does NOT
// abort — it only selects the inv poll. No hang possible.
// ---------------------------------------------------------------------------

__device__ __forceinline__ bool bar_wait(int* ctr, int rl)
{
    // drain own vm ops so everything published is complete before arrival
    asm volatile("s_waitcnt vmcnt(0)" ::: "memory");
    if (rl == 0)
        __hip_atomic_fetch_add(ctr, 1, __ATOMIC_RELAXED,
                               __HIP_MEMORY_SCOPE_AGENT);
    unsigned n = 0;
    while (__hip_atomic_load(ctr, __ATOMIC_RELAXED,
                             __HIP_MEMORY_SCOPE_AGENT) < NWAVE) {
        if (++n > BAR_LIMIT) return false;
    }
    return true;
}

__global__ __launch_bounds__(64, 1) void rnn_fast(
    const int*   __restrict__ x_idx,
    const float* __restrict__ W_xhT,   // NC x H
    const float* __restrict__ W_hh,
    const float* __restrict__ B_h,
    float*       __restrict__ h_all,   // (TT+1) x H
    u64*         __restrict__ pkt_st,  // [PRING][16][8][64]
    int*         __restrict__ ctrl,    // [0]=claim [1..3,6,7]=bars [4]=f1 [5]=f2
    u64*         __restrict__ probe,   // preflight-1 line (own 256B region)
    u64*         __restrict__ probe2,  // preflight-2 line (own 256B region)
    int*         __restrict__ done)    // completion counter, pre-zeroed
{
    // --- cohort self-assembly on XCD 0 ---
    unsigned xcc;
    asm volatile("s_getreg_b32 %0, hwreg(HW_REG_XCC_ID)" : "=s"(xcc));
    if ((xcc & 7u) != 0u) return;

    const int rl = threadIdx.x;
    int rank = 0;
    if (rl == 0)
        rank = __hip_atomic_fetch_add(&ctrl[0], 1, __ATOMIC_RELAXED,
                                      __HIP_MEMORY_SCOPE_AGENT);
    rank = __builtin_amdgcn_readfirstlane(rank);
    if (rank >= NWAVE) return;

    // --- preflight-1: EXACT r3/r7 sequence (frozen) ---
    if (rank == 0 && rl == 0)
        *probe = PF_MAGIC;               // plain store; bar1's vmcnt drains it

    if (!bar_wait(&ctrl[1], rl)) return;

    bool okI = false;
    {
        u64 pv = 0;
        for (unsigned n = 0; n < PF_LIMIT; ++n) {
            asm volatile(
                "buffer_inv sc0\n\t"
                "global_load_dwordx2 %0, %1, off\n\t"
                "s_waitcnt vmcnt(0)"
                : "=&v"(pv) : "v"(probe) : "memory");
            if (pv == (u64)PF_MAGIC) { okI = true; break; }
        }
    }
    if (!okI && rl == 0)
        __hip_atomic_fetch_add(&ctrl[4], 1, __ATOMIC_RELAXED,
                               __HIP_MEMORY_SCOPE_AGENT);
    if (!bar_wait(&ctrl[2], rl)) return;
    const bool modeINV =
        (__hip_atomic_load(&ctrl[4], __ATOMIC_RELAXED,
                           __HIP_MEMORY_SCOPE_AGENT) == 0);
    if (!modeINV) return;   // TELEMETRY: fast exit => rnn_fb runs (15 ms)

    // --- preflight-2: does the sc0 sc1 load flavor IGNORE stale L1? ---
    // prime L1 with the (stale, pre-zeroed) probe2 line
    {
        u64 primed;
        asm volatile(
            "global_load_dwordx2 %0, %1, off\n\t"
            "s_waitcnt vmcnt(0)"
            : "=&v"(primed) : "v"(probe2) : "memory");
        asm volatile("" :: "v"(primed));          // keep the prime alive
    }
    if (!bar_wait(&ctrl[3], rl)) return;          // all primes done

    if (rank == 0 && rl == 0)
        *probe2 = PF2_MAGIC;                      // plain store -> L2 dirty
    asm volatile("s_waitcnt vmcnt(0)" ::: "memory");

    bool okB = false;
    {
        u64 pv = 0;
        for (unsigned n = 0; n < PF2_LIMIT; ++n) {
            asm volatile(
                "global_load_dwordx2 %0, %1, off sc0 sc1\n\t"
                "s_waitcnt vmcnt(0)"
                : "=&v"(pv) : "v"(probe2) : "memory");
            if (pv == (u64)PF2_MAGIC) { okB = true; break; }
        }
    }
    if (!okB && rl == 0)
        __hip_atomic_fetch_add(&ctrl[5], 1, __ATOMIC_RELAXED,
                               __HIP_MEMORY_SCOPE_AGENT);
    if (!bar_wait(&ctrl[6], rl)) return;
    const bool need_inv =
        (__hip_atomic_load(&ctrl[5], __ATOMIC_RELAXED,
                           __HIP_MEMORY_SCOPE_AGENT) != 0);

    // --- setup ---
    const int b  = rank >> 3;                 // row slice 0..15
    const int cc = rank & 7;                  // col chunk 0..7
    const int row = b * SL + rl;              // producer row (<= 1023)
    const int e0  = cc * 128 + rl;            // consumer elements (e0 <= 959)
    const int e1  = e0 + 64;                  // (e1 <= 1023)
    const bool rowv = (row < H);
    const bool v1   = (e1 < H);

    float w[128];
    const float* wrow = W_hh + (size_t)row * H;
    #pragma unroll
    for (int q = 0; q < 32; ++q) {
        const int k = cc * 128 + 4 * q;
        float4 v = make_float4(0.f, 0.f, 0.f, 0.f);
        if (rowv && (k + 3) < H) v = *(const float4*)(wrow + k);
        w[4*q+0] = v.x; w[4*q+1] = v.y; w[4*q+2] = v.z; w[4*q+3] = v.w;
    }
    const float bi0 = B_h[e0];
    const float bi1 = v1 ? B_h[e1] : 0.f;

    __shared__ float sh[128];                 // my h-chunk
    sh[rl]      = h_all[e0];
    sh[64 + rl] = v1 ? h_all[e1] : 0.f;
    asm volatile("s_waitcnt lgkmcnt(0)" ::: "memory");

    int xi = x_idx[0];

    // ---- self-zero pkt_st (kills cross-run stale tags) ----
    const int gid = rank * SL + rl;               // 0..8191
    #pragma unroll
    for (int z = 0; z < 4; ++z)
        pkt_st[(size_t)z * 8192 + gid] = 0;       // 4*8192 = 32768 u64
    if (!bar_wait(&ctrl[7], rl)) return;

    const size_t slot_stride = 16 * 8 * 64;       // u64 per ring slot

    // ---- main loop ----
    for (int t = 1; t <= TT; ++t) {
        const int want = t;
        int xi_nxt = xi;
        if (want < TT) xi_nxt = x_idx[want];
        const float xh0 = W_xhT[(size_t)xi * H + e0];
        const float xh1 = v1 ? W_xhT[(size_t)xi * H + e1] : 0.f;

        float a;
        {
            float a0 = 0.f, a1 = 0.f, a2 = 0.f, a3 = 0.f;
            const float4* hb = (const float4*)sh;
            #pragma unroll
            for (int q = 0; q < 32; ++q) {
                const float4 hv4 = hb[q];
                a0 += w[4*q+0] * hv4.x;
                a1 += w[4*q+1] * hv4.y;
                a2 += w[4*q+2] * hv4.z;
                a3 += w[4*q+3] * hv4.w;
            }
            a = (a0 + a1) + (a2 + a3);
        }

        const int slot = want & (PRING - 1);
        // publish: wave-contiguous 512B plain store (r3/r7-proven pattern)
        pkt_st[slot * slot_stride + (((size_t)b * 8 + cc) * 64) + rl] =
            ((u64)(unsigned)want << 32) | (u64)__float_as_uint(a);
        asm volatile("" ::: "memory");

        // poll: [inv if unproven-bypass] + 16x dwordx2 sc0 sc1, ONE waitcnt
        const u64* base0 = pkt_st + slot * slot_stride
                         + ((size_t)(2 * cc)     * 8) * 64 + rl;
        const u64* base1 = pkt_st + slot * slot_stride
                         + ((size_t)(2 * cc + 1) * 8) * 64 + rl;
        u64 p00, p01, p02, p03, p04, p05, p06, p07;
        u64 p10, p11, p12, p13, p14, p15, p16, p17;
        const unsigned wtag = (unsigned)want;
        unsigned sweeps = 0;
        for (;;) {
            if (need_inv)
                asm volatile("buffer_inv sc0" ::: "memory");
            asm volatile(
                "global_load_dwordx2 %0, %16, off sc0 sc1\n\t"
                "global_load_dwordx2 %1, %16, off offset:512 sc0 sc1\n\t"
                "global_load_dwordx2 %2, %16, off offset:1024 sc0 sc1\n\t"
                "global_load_dwordx2 %3, %16, off offset:1536 sc0 sc1\n\t"
                "global_load_dwordx2 %4, %16, off offset:2048 sc0 sc1\n\t"
                "global_load_dwordx2 %5, %16, off offset:2560 sc0 sc1\n\t"
                "global_load_dwordx2 %6, %16, off offset:3072 sc0 sc1\n\t"
                "global_load_dwordx2 %7, %16, off offset:3584 sc0 sc1\n\t"
                "global_load_dwordx2 %8, %17, off sc0 sc1\n\t"
                "global_load_dwordx2 %9, %17, off offset:512 sc0 sc1\n\t"
                "global_load_dwordx2 %10, %17, off offset:1024 sc0 sc1\n\t"
                "global_load_dwordx2 %11, %17, off offset:1536 sc0 sc1\n\t"
                "global_load_dwordx2 %12, %17, off offset:2048 sc0 sc1\n\t"
                "global_load_dwordx2 %13, %17, off offset:2560 sc0 sc1\n\t"
                "global_load_dwordx2 %14, %17, off offset:3072 sc0 sc1\n\t"
                "global_load_dwordx2 %15, %17, off offset:3584 sc0 sc1\n\t"
                "s_waitcnt vmcnt(0)"
                : "=&v"(p00), "=&v"(p01), "=&v"(p02), "=&v"(p03),
                  "=&v"(p04), "=&v"(p05), "=&v"(p06), "=&v"(p07),
                  "=&v"(p10), "=&v"(p11), "=&v"(p12), "=&v"(p13),
                  "=&v"(p14), "=&v"(p15), "=&v"(p16), "=&v"(p17)
                : "v"(base0), "v"(base1)
                : "memory");
            bool ok = ((unsigned)(p00 >> 32) == wtag) &
                      ((unsigned)(p01 >> 32) == wtag) &
                      ((unsigned)(p02 >> 32) == wtag) &
                      ((unsigned)(p03 >> 32) == wtag) &
                      ((unsigned)(p04 >> 32) == wtag) &
                      ((unsigned)(p05 >> 32) == wtag) &
                      ((unsigned)(p06 >> 32) == wtag) &
                      ((unsigned)(p07 >> 32) == wtag) &
                      ((unsigned)(p10 >> 32) == wtag) &
                      ((unsigned)(p11 >> 32) == wtag) &
                      ((unsigned)(p12 >> 32) == wtag) &
                      ((unsigned)(p13 >> 32) == wtag) &
                      ((unsigned)(p14 >> 32) == wtag) &
                      ((unsigned)(p15 >> 32) == wtag) &
                      ((unsigned)(p16 >> 32) == wtag) &
                      ((unsigned)(p17 >> 32) == wtag);
            if (__all(ok)) break;
            if (++sweeps > POLL_LIMIT) return;   // cohort dead: bail
        }

        // fixed j-order sum => bit-identical across redundant finalizers
        float s0 = xh0 + bi0, s1 = xh1 + bi1;
        s0 += __uint_as_float((unsigned)p00);
        s0 += __uint_as_float((unsigned)p01);
        s0 += __uint_as_float((unsigned)p02);
        s0 += __uint_as_float((unsigned)p03);
        s0 += __uint_as_float((unsigned)p04);
        s0 += __uint_as_float((unsigned)p05);
        s0 += __uint_as_float((unsigned)p06);
        s0 += __uint_as_float((unsigned)p07);
        s1 += __uint_as_float((unsigned)p10);
        s1 += __uint_as_float((unsigned)p11);
        s1 += __uint_as_float((unsigned)p12);
        s1 += __uint_as_float((unsigned)p13);
        s1 += __uint_as_float((unsigned)p14);
        s1 += __uint_as_float((unsigned)p15);
        s1 += __uint_as_float((unsigned)p16);
        s1 += __uint_as_float((unsigned)p17);
        const float h0v = tanhf(s0);
        const float h1v = v1 ? tanhf(s1) : 0.f;
        if (want < TT) {
            sh[rl]      = h0v;
            sh[64 + rl] = h1v;
            asm volatile("s_waitcnt lgkmcnt(0)" ::: "memory");
        }
        if (b == cc) {                   // 8 designated writer waves
            h_all[(size_t)want * H + e0] = h0v;
            if (v1) h_all[(size_t)want * H + e1] = h1v;
        }
        xi = xi_nxt;
    }

    if (b == cc && rl == 0)
        __hip_atomic_fetch_add(done, 1, __ATOMIC_RELAXED,
                               __HIP_MEMORY_SCOPE_AGENT);
}

// ---------------------------------------------------------------------------
// FALLBACK: proven R3 agent-scope path (15.2ms). Skipped iff the fast cohort
// fully completed (done == 8) and the fast path was attempted (fail == 0).
// ---------------------------------------------------------------------------
#define FB_RING 4
__global__ __launch_bounds__(64) void rnn_fb(
    const int*   __restrict__ x_idx,
    const float* __restrict__ W_xhT,
    const float* __restrict__ W_hh,
    const float* __restrict__ B_h,
    float*       __restrict__ h_all,
    u64*         __restrict__ pkt,     // FB_RING x 16 x 16 x SL
    const int*   __restrict__ fail,
    const int*   __restrict__ done)
{
    if (__hip_atomic_load(fail, __ATOMIC_RELAXED,
                          __HIP_MEMORY_SCOPE_AGENT) == 0 &&
        __hip_atomic_load(done, __ATOMIC_RELAXED,
                          __HIP_MEMORY_SCOPE_AGENT) == 8)
        return;                               // fast path delivered h_all

    const int rl  = threadIdx.x;
    const int b   = blockIdx.x >> 4;
    const int cc  = blockIdx.x & 15;
    const int row = b * SL + rl;
    const int r   = cc * SL + rl;
    const bool rowv = (row < H);
    const bool rv   = (r < H);

    float w[SL];
    const float* wrow = W_hh + (size_t)row * H;
    #pragma unroll
    for (int q = 0; q < SL / 4; ++q) {
        const int k = cc * SL + 4 * q;
        float4 v = make_float4(0.f, 0.f, 0.f, 0.f);
        if (rowv && (k + 3) < H) v = *(const float4*)(wrow + k);
        w[4*q+0] = v.x; w[4*q+1] = v.y; w[4*q+2] = v.z; w[4*q+3] = v.w;
    }
    const float bh = rv ? B_h[r] : 0.f;

    __shared__ float sh[SL];
    sh[rl] = rv ? h_all[r] : 0.f;
    asm volatile("s_waitcnt lgkmcnt(0)" ::: "memory");

    int xi = x_idx[0];
    for (int t = 0; t < TT; ++t) {
        const unsigned want = (unsigned)(t + 1);
        const int slot = (int)(want & (FB_RING - 1));
        int xi_nxt = xi;
        if (t + 1 < TT) xi_nxt = x_idx[t + 1];
        float xh = 0.f;
        if (rv) xh = W_xhT[(size_t)xi * H + r];

        float a0 = 0.f, a1 = 0.f, a2 = 0.f, a3 = 0.f;
        const float4* hb = (const float4*)sh;
        #pragma unroll
        for (int q = 0; q < SL / 4; ++q) {
            const float4 hv4 = hb[q];
            a0 += w[4*q+0] * hv4.x;
            a1 += w[4*q+1] * hv4.y;
            a2 += w[4*q+2] * hv4.z;
            a3 += w[4*q+3] * hv4.w;
        }
        const float a = (a0 + a1) + (a2 + a3);

        __hip_atomic_store(pkt + (((size_t)slot * 16 + b) * 16 + cc) * SL + rl,
                           ((u64)want << 32) | (u64)__float_as_uint(a),
                           __ATOMIC_RELAXED, __HIP_MEMORY_SCOPE_AGENT);

        const u64* base = pkt + ((size_t)slot * 16 + cc) * 16 * SL + rl;
        u64 p[16];
        for (;;) {
            #pragma unroll
            for (int j = 0; j < 16; ++j)
                p[j] = __hip_atomic_load(base + j * SL, __ATOMIC_RELAXED,
                                         __HIP_MEMORY_SCOPE_AGENT);
            bool ok = true;
            #pragma unroll
            for (int j = 0; j < 16; ++j)
                ok &= ((unsigned)(p[j] >> 32) == want);
            if (__all(ok)) break;
        }

        float s = xh + bh;
        #pragma unroll
        for (int j = 0; j < 16; ++j) s += __uint_as_float((unsigned)p[j]);
        const float hv = rv ? tanhf(s) : 0.f;
        if (b == cc && rv) h_all[(size_t)want * H + r] = hv;
        sh[rl] = hv;
        asm volatile("s_waitcnt lgkmcnt(0)" ::: "memory");
        xi = xi_nxt;
    }
}

// ---------------------------------------------------------------------------
__global__ __launch_bounds__(256) void transpose_wxh(
    const float* __restrict__ W_xh, float* __restrict__ W_xhT)
{
    const int idx = blockIdx.x * 256 + threadIdx.x;
    if (idx < NC * H) {
        const int c = idx / H, r = idx % H;
        W_xhT[idx] = W_xh[r * NC + c];
    }
}

__global__ __launch_bounds__(256) void transpose_why(
    const float* __restrict__ W_hy, float* __restrict__ WhyT)
{
    const int idx = blockIdx.x * 256 + threadIdx.x;
    if (idx < NC * H) {
        const int k = idx / NC, n = idx % NC;
        WhyT[idx] = W_hy[n * H + k];
    }
}

__global__ __launch_bounds__(256) void out_gemm(
    const float* __restrict__ h_all,
    const float* __restrict__ WhyT,   // padded by >=16 floats
    float*       __restrict__ out)
{
    __shared__ float hs[TM * H];      // 64000 B
    const int t0 = blockIdx.x * TM;
    const int nt = min(TM, (TT + 1) - t0);

    const float4* src = (const float4*)(h_all + (size_t)t0 * H);
    const int total4 = nt * H / 4;
    for (int i = threadIdx.x; i < total4; i += 256)
        ((float4*)hs)[i] = src[i];
    __syncthreads();

    const int tl = threadIdx.x >> 4;
    const int ng = threadIdx.x & 15;
    if (tl < nt) {
        float acc0 = 0.f, acc1 = 0.f, acc2 = 0.f, acc3 = 0.f, acc4 = 0.f;
        const float* hrow = hs + tl * H;
        #pragma unroll 4
        for (int k = 0; k < H; ++k) {
            const float hv = hrow[k];
            const float* wr = WhyT + k * NC + ng;
            acc0 += hv * wr[0];
            acc1 += hv * wr[16];
            acc2 += hv * wr[32];
            acc3 += hv * wr[48];
            acc4 += hv * wr[64];
        }
        float* orow = out + (size_t)(t0 + tl) * NC + ng;
        orow[0]  = acc0;
        orow[16] = acc1;
        orow[32] = acc2;
        orow[48] = acc3;
        if (ng < 4) orow[64] = acc4;
    }
}

// ---------------------------------------------------------------------------
extern "C" void kernel_launch(void* const* d_in, const int* in_sizes, int n_in,
                              void* d_out, int out_size, void* d_ws, size_t ws_size,
                              hipStream_t stream)
{
    const int*   x_idx = (const int*)  d_in[0];
    const float* h0    = (const float*)d_in[1];
    const float* W_xh  = (const float*)d_in[2];
    const float* W_hh  = (const float*)d_in[3];
    const float* W_hy  = (const float*)d_in[4];
    const float* B_h   = (const float*)d_in[5];
    float* out = (float*)d_out;

    char* ws = (char*)d_ws;
    size_t off = 0;
    auto take = [&](size_t bytes) {
        void* p = ws + off;
        off = (off + bytes + 255) & ~(size_t)255;
        return p;
    };
    float* h_all  = (float*)take((size_t)(TT + 1) * H * sizeof(float));
    float* WhyT   = (float*)take((size_t)(NC * H + 32) * sizeof(float));
    float* W_xhT  = (float*)take((size_t)(NC * H) * sizeof(float));
    const size_t fb_bytes = (size_t)FB_RING * 16 * 16 * SL * sizeof(u64);
    u64*   pkt_fb = (u64*)take(fb_bytes);
    int*   fail   = (int*)take(64);
    int*   done   = (int*)take(64);
    int*   ctrl   = (int*)take(256);       // own cache lines
    u64*   probe  = (u64*)take(256);       // preflight-1 line
    u64*   probe2 = (u64*)take(256);       // preflight-2 line
    const size_t st_bytes = (size_t)PRING * 16 * 8 * 64 * sizeof(u64); // 256 KB
    u64*   pkt_st = (u64*)take(st_bytes);
    const size_t need_fast = off;

    hipMemcpyAsync(h_all, h0, H * sizeof(float),
                   hipMemcpyDeviceToDevice, stream);
    transpose_wxh<<<(NC * H + 255) / 256, 256, 0, stream>>>(W_xh, W_xhT);
    transpose_why<<<(NC * H + 255) / 256, 256, 0, stream>>>(W_hy, WhyT);

    hipMemsetAsync(pkt_fb, 0, fb_bytes, stream);
    hipMemsetAsync(done, 0, 64, stream);
    if (ws_size >= need_fast) {
        hipMemsetAsync(ctrl, 0, 256, stream);
        hipMemsetAsync(probe, 0, 256, stream);
        hipMemsetAsync(probe2, 0, 256, stream);
        hipMemsetAsync(fail, 0, 64, stream);
        rnn_fast<<<GRID_FAST, SL, 0, stream>>>(x_idx, W_xhT, W_hh, B_h,
                                               h_all, pkt_st,
                                               ctrl, probe, probe2, done);
    } else {
        hipMemsetAsync(fail, 1, 4, stream);    // force fallback
    }
    rnn_fb<<<256, SL, 0, stream>>>(x_idx, W_xhT, W_hh, B_h,
                                   h_all, pkt_fb, fail, done);
    out_gemm<<<(TT + 1 + TM - 1) / TM, 256, 0, stream>>>(h_all, WhyT, out);
}